// Round 8
// baseline (102.252 us; speedup 1.0000x reference)
//
#include <hip/hip_runtime.h>
#include <hip/hip_bf16.h>

// AttentivePooling: B=32, S=8192, C=256, MID=128, fp32 in/out.
// out[b,c] = sum_s softmax_s( tanh(x@W1+b1)@w2 )[b,s] * x[b,s,c]   (b2 shift-invariant)
//
// R8: row-slab streaming. Each block: 128 rows x 256 cols tile, staged as
// 4 x 32KB FULLY-CONTIGUOUS slabs (32 rows x 1KB) via global_load_lds DMA,
// double-buffered, counted vmcnt(8). Waves = 4 column-quarters (x4 LDS reuse).
// All W fragments preloaded to registers -> K-loop vmem = DMA only.
// Swizzle (row&7)<<4 both-sides (16B-granular, DMA-preserved, conflict-free).

typedef __attribute__((ext_vector_type(8))) short short8;
typedef __attribute__((ext_vector_type(4))) float f32x4;
typedef unsigned short u16;

constexpr int Bb = 32;
constexpr int Ss = 8192;
constexpr int Cc = 256;
constexpr int MIDm = 128;
constexpr int BM = 128;              // rows per block
constexpr int NBLK = Bb * Ss / BM;   // 2048
constexpr int BPB = Ss / BM;         // 64 blocks per batch

__device__ __forceinline__ u16 f2bf(float f) {
  return __builtin_bit_cast(u16, __float2bfloat16(f));   // RNE
}

// ---- one-time prep: W fragments, frag-major for the 4-column-wave scheme ----
// t = ((wc*8 + kcc)*2 + nt)*64 + lane  -> 8 bf16 (16B):
//   n = wc*32 + nt*16 + (lane&15),  k = kcc*32 + (lane>>4)*8 + e
__global__ __launch_bounds__(256) void wprep_kernel(
    const float* __restrict__ W1, u16* __restrict__ FB)
{
  const int t    = blockIdx.x * 256 + threadIdx.x;   // 0..4095
  const int lane = t & 63;
  const int nt   = (t >> 6) & 1;
  const int kcc  = (t >> 7) & 7;
  const int wc   = (t >> 10) & 3;
  const int n    = wc * 32 + nt * 16 + (lane & 15);
  const int k0   = kcc * 32 + (lane >> 4) * 8;
  union { u16 v[8]; short8 s; } u;
  #pragma unroll
  for (int e = 0; e < 8; ++e) u.v[e] = f2bf(W1[(size_t)(k0 + e) * MIDm + n]);
  *(short8*)(FB + (size_t)t * 8) = u.s;
}

// ---- fused: slab-DMA MFMA scores -> block softmax -> weighted x partial ----
__global__ __launch_bounds__(256, 2) void fused_kernel(
    const float* __restrict__ x, const u16* __restrict__ FB,
    const float* __restrict__ b1, const float* __restrict__ w2,
    float* __restrict__ oPart, float* __restrict__ mPart, float* __restrict__ lPart)
{
  __shared__ __align__(16) char smem[65536];   // 2 x 32KB slab buffers
  const int tid  = threadIdx.x;
  const int lane = tid & 63;
  const int w    = tid >> 6;        // wave = column quarter (0..3)
  const int q    = lane >> 4;       // k-group
  const int ln   = lane & 15;       // frag row/col index
  const int row0 = blockIdx.x * BM;

  // ---- preload ALL W fragments into registers (L2-hot, once per block) ----
  short8 Bf[8][2];
  {
    const u16* fbw = FB + ((size_t)(w * 8) * 2 + 0) * 64 * 8;
    #pragma unroll
    for (int kcc = 0; kcc < 8; ++kcc)
      #pragma unroll
      for (int nt = 0; nt < 2; ++nt)
        Bf[kcc][nt] = *(const short8*)(FB +
            ((size_t)(((w * 8 + kcc) * 2 + nt) * 64 + lane)) * 8);
    (void)fbw;
  }

  // acc[slab][mt][nt], init with b1[col]
  f32x4 acc[4][2][2];
  #pragma unroll
  for (int nt = 0; nt < 2; ++nt) {
    float bj = b1[32 * w + 16 * nt + ln];
    #pragma unroll
    for (int sl = 0; sl < 4; ++sl)
      #pragma unroll
      for (int mt = 0; mt < 2; ++mt) {
        acc[sl][mt][nt][0] = bj; acc[sl][mt][nt][1] = bj;
        acc[sl][mt][nt][2] = bj; acc[sl][mt][nt][3] = bj;
      }
  }

  // STAGE slab sl (32 rows x 1KB, contiguous 32KB) into buffer buf.
  // LDS byte L (row=L>>10, inrow=L&1023) holds global inrow ^ ((row&7)<<4).
  #define STAGE(buf, sl)                                                              \
    {                                                                                 \
      _Pragma("unroll")                                                               \
      for (int r = 0; r < 8; ++r) {                                                   \
        int L     = r * 4096 + tid * 16;                                              \
        int row   = L >> 10;                                                          \
        int inrow = (L & 1023) ^ ((row & 7) << 4);                                    \
        const char* src = (const char*)x                                              \
            + (size_t)(row0 + (sl) * 32 + row) * 1024 + inrow;                        \
        __builtin_amdgcn_global_load_lds(                                             \
            (const __attribute__((address_space(1))) void*)src,                       \
            (__attribute__((address_space(3))) void*)(smem + (buf) * 32768 + L),      \
            16, 0, 0);                                                                \
      }                                                                               \
    }

  STAGE(0, 0);

  #pragma unroll
  for (int sl = 0; sl < 4; ++sl) {
    const int cur = sl & 1;
    if (sl < 3) STAGE(1 - cur, sl + 1);   // safe: buf read finished at sl-1 bottom barrier

    __builtin_amdgcn_sched_barrier(0);
    if (sl < 3) asm volatile("s_waitcnt vmcnt(8)" ::: "memory");  // slab sl landed, sl+1 flying
    else        asm volatile("s_waitcnt vmcnt(0)" ::: "memory");
    __builtin_amdgcn_sched_barrier(0);
    __builtin_amdgcn_s_barrier();
    __builtin_amdgcn_sched_barrier(0);

    const char* bufb = smem + cur * 32768;
    #pragma unroll
    for (int kcc = 0; kcc < 8; ++kcc) {
      #pragma unroll
      for (int mt = 0; mt < 2; ++mt) {
        const int row = 16 * mt + ln;
        const int sw  = (row & 7) << 4;
        const char* base = bufb + row * 1024;
        const int off = kcc * 128 + q * 32;
        float4 lo = *(const float4*)(base + (off ^ sw));
        float4 hi = *(const float4*)(base + ((off + 16) ^ sw));
        union { u16 v[8]; short8 s8; } t8;
        t8.v[0] = f2bf(lo.x); t8.v[1] = f2bf(lo.y); t8.v[2] = f2bf(lo.z); t8.v[3] = f2bf(lo.w);
        t8.v[4] = f2bf(hi.x); t8.v[5] = f2bf(hi.y); t8.v[6] = f2bf(hi.z); t8.v[7] = f2bf(hi.w);
        #pragma unroll
        for (int nt = 0; nt < 2; ++nt)
          acc[sl][mt][nt] = __builtin_amdgcn_mfma_f32_16x16x32_bf16(
              t8.s8, Bf[kcc][nt], acc[sl][mt][nt], 0, 0, 0);
      }
    }

    __builtin_amdgcn_sched_barrier(0);
    __builtin_amdgcn_s_barrier();
  }

  // ---- epilogue overlay on buf0 (all buf0 reads ended at slab2's barrier) ----
  float* sScore = (float*)smem;            // [4][128] per-wave partials
  float* sP     = (float*)(smem + 2048);   // [128]
  float* sO     = (float*)(smem + 2560);   // [4][256]
  float* sML    = (float*)(smem + 6656);   // m, l

  float w2v[2];
  #pragma unroll
  for (int nt = 0; nt < 2; ++nt) w2v[nt] = w2[32 * w + 16 * nt + ln];

  #pragma unroll
  for (int sl = 0; sl < 4; ++sl)
    #pragma unroll
    for (int mt = 0; mt < 2; ++mt) {
      float p[4];
      #pragma unroll
      for (int r = 0; r < 4; ++r) p[r] = 0.f;
      #pragma unroll
      for (int nt = 0; nt < 2; ++nt)
        #pragma unroll
        for (int r = 0; r < 4; ++r)
          p[r] += (1.0f - 2.0f / (__expf(2.0f * acc[sl][mt][nt][r]) + 1.0f)) * w2v[nt];
      #pragma unroll
      for (int off = 1; off < 16; off <<= 1)
        #pragma unroll
        for (int r = 0; r < 4; ++r) p[r] += __shfl_xor(p[r], off);
      if (ln == 0) {
        #pragma unroll
        for (int r = 0; r < 4; ++r)
          sScore[w * BM + 32 * sl + 16 * mt + 4 * q + r] = p[r];
      }
    }
  __syncthreads();

  // block-local softmax partials
  if (tid < BM)
    sP[tid] = sScore[tid] + sScore[BM + tid] + sScore[2 * BM + tid] + sScore[3 * BM + tid];
  __syncthreads();
  if (w == 0) {
    float a = sP[lane], b = sP[lane + 64];
    float m = fmaxf(a, b);
    #pragma unroll
    for (int off = 1; off < 64; off <<= 1) m = fmaxf(m, __shfl_xor(m, off));
    float e0 = __expf(a - m), e1 = __expf(b - m);
    sP[lane] = e0; sP[lane + 64] = e1;
    float s = e0 + e1;
    #pragma unroll
    for (int off = 1; off < 64; off <<= 1) s += __shfl_xor(s, off);
    if (lane == 0) { sML[0] = m; sML[1] = s; }
  }
  __syncthreads();

  // weighted x partial: o[c] = sum_r sP[r] * x[row0+r][c]  (L2/L3-hot re-read)
  const int c4 = tid & 63;
  const int rg = tid >> 6;
  const float* xo = x + (size_t)(row0 + rg * 32) * Cc + c4 * 4;
  float4 o = make_float4(0.f, 0.f, 0.f, 0.f);
  #pragma unroll 8
  for (int r = 0; r < 32; ++r) {
    float pw = sP[rg * 32 + r];
    float4 xv = *(const float4*)(xo + (size_t)r * Cc);
    o.x = fmaf(pw, xv.x, o.x);
    o.y = fmaf(pw, xv.y, o.y);
    o.z = fmaf(pw, xv.z, o.z);
    o.w = fmaf(pw, xv.w, o.w);
  }
  *(float4*)&sO[rg * Cc + c4 * 4] = o;
  __syncthreads();

  float oc = sO[tid] + sO[Cc + tid] + sO[2 * Cc + tid] + sO[3 * Cc + tid];
  oPart[(size_t)blockIdx.x * Cc + tid] = oc;
  if (tid == 0) { mPart[blockIdx.x] = sML[0]; lPart[blockIdx.x] = sML[1]; }
}

// ---- combine 64 block partials per batch (deterministic) ----
__global__ __launch_bounds__(256) void combine_kernel(
    const float* __restrict__ oPart, const float* __restrict__ mPart,
    const float* __restrict__ lPart, float* __restrict__ out)
{
  const int b = blockIdx.x;
  const int t = threadIdx.x;
  float M = -3.4e38f;
  for (int k = 0; k < BPB; ++k) M = fmaxf(M, mPart[b * BPB + k]);
  float num = 0.f, den = 0.f;
  for (int k = 0; k < BPB; ++k) {
    float wgt = __expf(mPart[b * BPB + k] - M);
    den += wgt * lPart[b * BPB + k];
    num = fmaf(wgt, oPart[(size_t)(b * BPB + k) * Cc + t], num);
  }
  out[b * Cc + t] = num / den;
}

extern "C" void kernel_launch(void* const* d_in, const int* in_sizes, int n_in,
                              void* d_out, int out_size, void* d_ws, size_t ws_size,
                              hipStream_t stream)
{
  const float* x  = (const float*)d_in[0];
  const float* W1 = (const float*)d_in[1];
  const float* b1 = (const float*)d_in[2];
  const float* w2 = (const float*)d_in[3];
  // d_in[4] = b2: unused (softmax shift-invariant)
  float* out = (float*)d_out;

  u16*   FB    = (u16*)d_ws;                                  // 64 KB frag-major W
  float* oPart = (float*)((char*)d_ws + 65536);               // 2 MB
  float* mPart = (float*)((char*)d_ws + 65536 + 2097152);     // 8 KB
  float* lPart = (float*)((char*)d_ws + 65536 + 2097152 + 8192);

  wprep_kernel<<<16, 256, 0, stream>>>(W1, FB);
  fused_kernel<<<NBLK, 256, 0, stream>>>(x, FB, b1, w2, oPart, mPart, lPart);
  combine_kernel<<<Bb, Cc, 0, stream>>>(oPart, mPart, lPart, out);
}